// Round 8
// baseline (1212.599 us; speedup 1.0000x reference)
//
#include <hip/hip_runtime.h>

#define TSTEPS 20
#define THRESV 1.0f
#define DECAYV 0.9375f

// Slice partials, double-buffered by step parity: [par][slice rs][8192 cols].
// Written fully each step before being read (counter-gated) => deterministic.
__device__ float g_p1[2][32][8192];
__device__ float g_p2[2][32][8192];

// ws byte layout:
//   [0,      7680)   u64 s_in_bits[20][48]
//   [7680,  28160)   u64 s1_bits[20][128]
//   [28160, 48640)   u64 s2_bits[20][128]
//   [48640, 48720)   u32 gcnt1[20]
//   [48720, 48800)   u32 gcnt2[20]
//   [48800, 48880)   u32 rcnt1[20]
//   [48880, 48960)   u32 rcnt2[20]      (all counters memset 0 each launch)

__global__ void snn_input_kernel(const float* __restrict__ image,
                                 unsigned long long* __restrict__ s_in_bits) {
    int i = blockIdx.x * 256 + threadIdx.x;   // 0..3071
    float img = image[i];
    float mi = 0.f;
    int word = i >> 6, lane = i & 63;
    for (int t = 0; t < TSTEPS; ++t) {
        mi += img;
        bool fire = (mi >= THRESV);
        if (fire) mi -= THRESV;
        unsigned long long bm = __ballot(fire);
        if (lane == 0) s_in_bits[t * 48 + word] = bm;
    }
}

struct SMem {
    unsigned short list[8192];      // 16 KiB compacted firing-row indices
    unsigned long long bw[128];
    unsigned pc[128];
    int cntp;
    float mcol[64];                 // persistent membrane slice (reducer role)
    float partials[512];            // layer-3 path only
};

__device__ __forceinline__ void wait_cnt(const unsigned* p, unsigned target) {
    if (threadIdx.x == 0) {
        while (__hip_atomic_load(p, __ATOMIC_ACQUIRE, __HIP_MEMORY_SCOPE_AGENT) < target)
            __builtin_amdgcn_s_sleep(16);
    }
    __syncthreads();
}

// Deterministic parallel compaction (ascending list order).
template <int NW>
__device__ __forceinline__ int compact_par(const unsigned long long* bits, SMem& sm) {
    int tid = threadIdx.x;
    if (tid < NW) {
        unsigned long long w = __hip_atomic_load(&bits[tid], __ATOMIC_RELAXED, __HIP_MEMORY_SCOPE_AGENT);
        sm.bw[tid] = w;
        sm.pc[tid] = (unsigned)__popcll(w);
    }
    __syncthreads();
    constexpr int WPW = NW / 8;
    int wave = tid >> 6, lane = tid & 63;
    int w0 = wave * WPW;
    int base = 0;
    for (int i = lane; i < w0; i += 64) base += (int)sm.pc[i];
    #pragma unroll
    for (int off = 1; off < 64; off <<= 1) base += __shfl_xor(base, off);
    if (wave == 0) {
        int tot = 0;
        for (int i = lane; i < NW; i += 64) tot += (int)sm.pc[i];
        #pragma unroll
        for (int off = 1; off < 64; off <<= 1) tot += __shfl_xor(tot, off);
        if (lane == 0) sm.cntp = tot;
    }
    for (int i = 0; i < WPW; ++i) {
        unsigned long long w = sm.bw[w0 + i];
        if ((w >> lane) & 1ull) {
            int pos = base + __popcll(w & ((1ull << lane) - 1ull));
            sm.list[pos] = (unsigned short)(((w0 + i) << 6) + lane);
        }
        base += __popcll(w);
    }
    __syncthreads();
    return sm.cntp;
}

// Gather one strided row-slice (k = rs, rs+32, ...) restricted to a 1024-col
// group: per row the block reads 4 KB CONTIGUOUS (512 thr x float2).
// Per-col add chain = ascending k, identical to round-2's group-rs partial
// => bitwise-identical values.
__device__ __forceinline__ void gather_slice(const float* __restrict__ W, int count,
                                             SMem& sm, int rs, int cg,
                                             float* __restrict__ pOut) {
    int tid = threadIdx.x;
    const float* base = W + (size_t)cg * 1024 + 2 * tid;
    float a0 = 0.f, a1 = 0.f;
    int k = rs;
    for (; k + 96 < count; k += 128) {               // 4 rows in flight
        float2 v0 = *(const float2*)(base + (size_t)sm.list[k]      * 8192);
        float2 v1 = *(const float2*)(base + (size_t)sm.list[k + 32] * 8192);
        float2 v2 = *(const float2*)(base + (size_t)sm.list[k + 64] * 8192);
        float2 v3 = *(const float2*)(base + (size_t)sm.list[k + 96] * 8192);
        a0 += v0.x; a1 += v0.y;
        a0 += v1.x; a1 += v1.y;
        a0 += v2.x; a1 += v2.y;
        a0 += v3.x; a1 += v3.y;
    }
    for (; k < count; k += 32) {
        float2 v = *(const float2*)(base + (size_t)sm.list[k] * 8192);
        a0 += v.x; a1 += v.y;
    }
    *(float2*)(pOut + 2 * tid) = make_float2(a0, a1);
}

// Sum the 32 slice-partials for one 64-col word in ascending slice order
// (exact round-2 chain), then LIF + publish spike word.
__device__ __forceinline__ void reduce_word(const float (*__restrict__ p)[8192], int w,
                                            SMem& sm, unsigned long long* dst_word,
                                            unsigned* cnt_pub) {
    int tid = threadIdx.x;
    if (tid < 64) {
        int j = w * 64 + tid;
        float s = 0.f;
        #pragma unroll
        for (int gg = 0; gg < 32; ++gg) s += p[gg][j];
        float v = sm.mcol[tid] + s;
        bool fire = (v >= THRESV);
        if (fire) v -= THRESV;
        sm.mcol[tid] = fire ? v : v * DECAYV;
        unsigned long long bm = __ballot(fire);
        if (tid == 0) {
            __hip_atomic_store(dst_word, bm, __ATOMIC_RELEASE, __HIP_MEMORY_SCOPE_AGENT);
            __hip_atomic_fetch_add(cnt_pub, 1u, __ATOMIC_RELEASE, __HIP_MEMORY_SCOPE_AGENT);
        }
    }
    __syncthreads();
}

__global__ void __launch_bounds__(512, 1)
snn_persistent(const float* __restrict__ W1, const float* __restrict__ W2,
               const float* __restrict__ W3,
               const unsigned long long* __restrict__ s_in_bits,
               unsigned long long* __restrict__ s1_bits,
               unsigned long long* __restrict__ s2_bits,
               unsigned* __restrict__ gcnt1, unsigned* __restrict__ gcnt2,
               unsigned* __restrict__ rcnt1, unsigned* __restrict__ rcnt2,
               float* __restrict__ out) {
    __shared__ __align__(16) SMem sm;
    int tid = threadIdx.x;
    int b = blockIdx.x;
    if (tid < 64) sm.mcol[tid] = 0.f;
    __syncthreads();

    if (b < 256) {
        int cg = b >> 5;        // col-group 0..7 (1024 cols)
        int rs = b & 31;        // row-slice 0..31 (k = rs mod 32)
        for (int t = 0; t < TSTEPS; ++t) {
            int par = t & 1;
            // ---- L1 gather: depends only on precomputed input spikes ----
            int c1 = compact_par<48>(s_in_bits + (size_t)t * 48, sm);
            gather_slice(W1, c1, sm, rs, cg, &g_p1[par][rs][cg * 1024]);
            __syncthreads();   // drain stores before signaling
            if (tid == 0)
                __hip_atomic_fetch_add(&gcnt1[t], 1u, __ATOMIC_RELEASE, __HIP_MEMORY_SCOPE_AGENT);

            // ---- L2 gather: consumes s1[t-1] ----
            if (t >= 1) {
                wait_cnt(&rcnt1[t - 1], 128);
                int c2 = compact_par<128>(s1_bits + (size_t)(t - 1) * 128, sm);
                gather_slice(W2, c2, sm, rs, cg, &g_p2[par][rs][cg * 1024]);
                __syncthreads();
                if (tid == 0)
                    __hip_atomic_fetch_add(&gcnt2[t], 1u, __ATOMIC_RELEASE, __HIP_MEMORY_SCOPE_AGENT);
            }

            // ---- reduce role ----
            if (b < 128) {
                wait_cnt(&gcnt1[t], 256);
                reduce_word(g_p1[par], b, sm, &s1_bits[t * 128 + b], &rcnt1[t]);
            } else if (t == 0) {
                // step 0: zero L2 input -> no fire, membrane stays 0
                if (tid == 0) {
                    __hip_atomic_store(&s2_bits[b - 128], 0ull, __ATOMIC_RELEASE, __HIP_MEMORY_SCOPE_AGENT);
                    __hip_atomic_fetch_add(&rcnt2[0], 1u, __ATOMIC_RELEASE, __HIP_MEMORY_SCOPE_AGENT);
                }
                __syncthreads();
            } else {
                wait_cnt(&gcnt2[t], 256);
                reduce_word(g_p2[par], b - 128, sm, &s2_bits[t * 128 + (b - 128)], &rcnt2[t]);
            }
        }
    } else {
        // ---- layer-3 role (single block): consumes s2[t-1] ----
        if (tid < 10) { out[tid] = 0.f; out[10 + tid] = 0.f; }  // rows 0,1
        for (int t = 1; t < TSTEPS; ++t) {
            wait_cnt(&rcnt2[t - 1], 128);
            int count = compact_par<128>(s2_bits + (size_t)(t - 1) * 128, sm);
            int col = tid & 15, g = tid >> 4;                    // 32 groups
            float acc = 0.f;
            if (col < 10) {
                for (int k = g; k < count; k += 32)
                    acc += W3[(size_t)sm.list[k] * 10 + col];
            }
            sm.partials[g * 16 + col] = acc;
            __syncthreads();
            if (tid < 10) {
                float s = 0.f;
                for (int gg = 0; gg < 32; ++gg) s += sm.partials[gg * 16 + tid];
                float v = sm.mcol[tid] + s;
                bool fire = (v >= THRESV);
                if (fire) v -= THRESV;
                sm.mcol[tid] = fire ? v : v * DECAYV;
                out[(t + 1) * 10 + tid] = fire ? 1.f : 0.f;
            }
            __syncthreads();
        }
    }
}

extern "C" void kernel_launch(void* const* d_in, const int* in_sizes, int n_in,
                              void* d_out, int out_size, void* d_ws, size_t ws_size,
                              hipStream_t stream) {
    const float* image = (const float*)d_in[0];
    const float* W1 = (const float*)d_in[1];
    const float* W2 = (const float*)d_in[2];
    const float* W3 = (const float*)d_in[3];
    float* out = (float*)d_out;

    char* ws = (char*)d_ws;
    unsigned long long* s_in_bits = (unsigned long long*)ws;            // [20][48]
    unsigned long long* s1_bits = (unsigned long long*)(ws + 7680);     // [20][128]
    unsigned long long* s2_bits = (unsigned long long*)(ws + 28160);    // [20][128]
    unsigned* gcnt1 = (unsigned*)(ws + 48640);                          // [20]
    unsigned* gcnt2 = (unsigned*)(ws + 48720);                          // [20]
    unsigned* rcnt1 = (unsigned*)(ws + 48800);                          // [20]
    unsigned* rcnt2 = (unsigned*)(ws + 48880);                          // [20]

    // counters must be zero before the persistent kernel starts (each replay)
    hipMemsetAsync(ws + 48640, 0, 320, stream);

    snn_input_kernel<<<12, 256, 0, stream>>>(image, s_in_bits);

    snn_persistent<<<257, 512, 0, stream>>>(W1, W2, W3, s_in_bits,
                                            s1_bits, s2_bits,
                                            gcnt1, gcnt2, rcnt1, rcnt2, out);
}